// Round 5
// baseline (676.844 us; speedup 1.0000x reference)
//
#include <hip/hip_runtime.h>
#include <hip/hip_bf16.h>

#define N_ROWS 65536
#define DIM    2048
#define NEXP   8
#define TOPK   2
#define RPW    2                   // rows per wave per iteration (small => no spill)
#define CHUNKS (DIM / (64 * 4))    // 8 float4-chunks per row per lane
#define BLOCK  256
#define GRID   2048                // 8192 waves -> 4 row-groups each

typedef float f4 __attribute__((ext_vector_type(4)));

// No LDS: W is 64 KiB total, read by every wave at the same addresses ->
// L1/L2 resident. LDS staging cost us occupancy (2 blocks/CU) in R1 and
// forced a VGPR=32 spill-fest in R3/R4. VGPR-only occupancy: 64 VGPR cap
// via __launch_bounds__(256,4) -> 8 waves/SIMD.
__global__ __launch_bounds__(BLOCK, 4) void moe_router_kernel(
    const float* __restrict__ x,
    const float* __restrict__ W,
    const float* __restrict__ b,
    float* __restrict__ out_vals,   // [N, 2] f32
    float* __restrict__ out_idx,    // [N, 2] written as f32
    float* __restrict__ out_x)      // [N, D] f32 (pass-through copy)
{
    const int lane   = threadIdx.x & 63;
    const int wave   = (int)((blockIdx.x * BLOCK + threadIdx.x) >> 6);
    const int nwaves = (GRID * BLOCK) >> 6;

    const f4* x4 = (const f4*)x;
    const f4* W4 = (const f4*)W;
    f4* ox4 = (f4*)out_x;
    const int row_f4 = DIM / 4;   // 512 float4s per row

    for (int g = wave; g < N_ROWS / RPW; g += nwaves) {
        const int row0 = g * RPW;

        float acc[RPW][NEXP];
#pragma unroll
        for (int r = 0; r < RPW; ++r)
#pragma unroll
            for (int e = 0; e < NEXP; ++e) acc[r][e] = 0.0f;

#pragma unroll
        for (int c = 0; c < CHUNKS; ++c) {
            const int d4 = c * 64 + lane;           // float4 index within row
            f4 xv[RPW];
#pragma unroll
            for (int r = 0; r < RPW; ++r) {
                const size_t off = (size_t)(row0 + r) * row_f4 + d4;
                xv[r] = x4[off];
                ox4[off] = xv[r];                   // fused pass-through copy
            }
#pragma unroll
            for (int e = 0; e < NEXP; ++e) {
                const f4 wv = W4[e * row_f4 + d4];  // L1/L2-resident
#pragma unroll
                for (int r = 0; r < RPW; ++r) {
                    acc[r][e] += xv[r].x * wv.x;
                    acc[r][e] += xv[r].y * wv.y;
                    acc[r][e] += xv[r].z * wv.z;
                    acc[r][e] += xv[r].w * wv.w;
                }
            }
        }

        // Wave-wide butterfly reduce: every lane ends with the full dot product.
#pragma unroll
        for (int r = 0; r < RPW; ++r) {
#pragma unroll
            for (int e = 0; e < NEXP; ++e) {
                float v = acc[r][e];
                v += __shfl_xor(v, 32, 64);
                v += __shfl_xor(v, 16, 64);
                v += __shfl_xor(v, 8, 64);
                v += __shfl_xor(v, 4, 64);
                v += __shfl_xor(v, 2, 64);
                v += __shfl_xor(v, 1, 64);
                acc[r][e] = v + b[e];
            }
        }

        // Lanes 0..RPW-1 finish one row each: softmax over 8, top-2.
        if (lane < RPW) {
            const int r = lane;
            float lg[NEXP];
#pragma unroll
            for (int e = 0; e < NEXP; ++e) lg[e] = acc[r][e];

            float mx = lg[0];
#pragma unroll
            for (int e = 1; e < NEXP; ++e) mx = fmaxf(mx, lg[e]);

            float p[NEXP];
            float sum = 0.0f;
#pragma unroll
            for (int e = 0; e < NEXP; ++e) { p[e] = __expf(lg[e] - mx); sum += p[e]; }
            const float inv = 1.0f / sum;

            // top-1: strict > keeps the lowest index on ties (jax.lax.top_k order)
            int i1 = 0;
#pragma unroll
            for (int e = 1; e < NEXP; ++e) if (lg[e] > lg[i1]) i1 = e;
            // top-2: lowest-index-first among the rest
            int i2 = (i1 == 0) ? 1 : 0;
#pragma unroll
            for (int e = 0; e < NEXP; ++e)
                if (e != i1 && e != i2 && lg[e] > lg[i2]) i2 = e;

            const int row = row0 + r;
            out_vals[row * 2 + 0] = p[i1] * inv;
            out_vals[row * 2 + 1] = p[i2] * inv;
            out_idx[row * 2 + 0]  = (float)i1;
            out_idx[row * 2 + 1]  = (float)i2;
        }
    }
}

extern "C" void kernel_launch(void* const* d_in, const int* in_sizes, int n_in,
                              void* d_out, int out_size, void* d_ws, size_t ws_size,
                              hipStream_t stream) {
    const float* x = (const float*)d_in[0];
    const float* W = (const float*)d_in[1];
    const float* b = (const float*)d_in[2];

    float* out = (float*)d_out;
    float* out_vals = out;                       // N*2
    float* out_idx  = out + (size_t)N_ROWS * 2;  // N*2
    float* out_x    = out + (size_t)N_ROWS * 4;  // N*D

    moe_router_kernel<<<GRID, BLOCK, 0, stream>>>(x, W, b, out_vals, out_idx, out_x);
}

// Round 6
// 223.553 us; speedup vs baseline: 3.0277x; 3.0277x over previous
//
#include <hip/hip_runtime.h>
#include <hip/hip_bf16.h>

#define N_ROWS 65536
#define DIM    2048
#define NEXP   8
#define TOPK   2
#define RPW    2                   // rows per wave per iteration (keeps acc file small)
#define CHUNKS (DIM / (64 * 4))    // 8 float4-chunks per row per lane
#define BLOCK  1024                // 16 waves/block
#define GRID   512                 // 2 blocks/CU; 8192 waves; 32768/8192 = 4 iters exact

typedef float f4 __attribute__((ext_vector_type(4)));

// R1 structure (LDS-staged f32 W = clean traffic) at 2x the occupancy:
// 1024-thr blocks, 64 KiB LDS -> 2 blocks/CU = 32 waves/CU, valid iff VGPR<=64.
// RPW=2 + unroll 2 keeps the live set ~60 regs. launch_bounds(1024,4) caps at
// 128 so a miss degrades to 1 block/CU (R1-level), not a spill cliff.
__global__ __launch_bounds__(BLOCK, 4) void moe_router_kernel(
    const float* __restrict__ x,
    const float* __restrict__ W,
    const float* __restrict__ b,
    float* __restrict__ out_vals,   // [N, 2] f32
    float* __restrict__ out_idx,    // [N, 2] written as f32
    float* __restrict__ out_x)      // [N, D] f32 (pass-through copy)
{
    __shared__ float sW[NEXP * DIM];   // 64 KiB

    // Cooperative stage of W into LDS (vectorized, coalesced).
    const f4* W4 = (const f4*)W;
    f4* sW4 = (f4*)sW;
    for (int i = threadIdx.x; i < NEXP * DIM / 4; i += BLOCK)
        sW4[i] = W4[i];
    __syncthreads();

    const int lane   = threadIdx.x & 63;
    const int wave   = (int)((blockIdx.x * BLOCK + threadIdx.x) >> 6);
    const int nwaves = (GRID * BLOCK) >> 6;

    const f4* x4 = (const f4*)x;
    f4* ox4 = (f4*)out_x;
    const int row_f4 = DIM / 4;   // 512 float4s per row

    for (int g = wave; g < N_ROWS / RPW; g += nwaves) {
        const int row0 = g * RPW;

        float acc[RPW][NEXP];
#pragma unroll
        for (int r = 0; r < RPW; ++r)
#pragma unroll
            for (int e = 0; e < NEXP; ++e) acc[r][e] = 0.0f;

#pragma unroll 2
        for (int c = 0; c < CHUNKS; ++c) {
            const int d4 = c * 64 + lane;           // float4 index within row
            f4 xv[RPW];
#pragma unroll
            for (int r = 0; r < RPW; ++r) {
                const size_t off = (size_t)(row0 + r) * row_f4 + d4;
                xv[r] = x4[off];
                ox4[off] = xv[r];                   // fused pass-through copy
            }
#pragma unroll
            for (int e = 0; e < NEXP; ++e) {
                const f4 wv = sW4[e * row_f4 + d4];
#pragma unroll
                for (int r = 0; r < RPW; ++r) {
                    acc[r][e] += xv[r].x * wv.x;
                    acc[r][e] += xv[r].y * wv.y;
                    acc[r][e] += xv[r].z * wv.z;
                    acc[r][e] += xv[r].w * wv.w;
                }
            }
        }

        // Wave-wide butterfly reduce: every lane ends with the full dot product.
#pragma unroll
        for (int r = 0; r < RPW; ++r) {
#pragma unroll
            for (int e = 0; e < NEXP; ++e) {
                float v = acc[r][e];
                v += __shfl_xor(v, 32, 64);
                v += __shfl_xor(v, 16, 64);
                v += __shfl_xor(v, 8, 64);
                v += __shfl_xor(v, 4, 64);
                v += __shfl_xor(v, 2, 64);
                v += __shfl_xor(v, 1, 64);
                acc[r][e] = v;
            }
        }

        // Lanes 0..RPW-1 finish one row each: bias, softmax over 8, top-2.
        if (lane < RPW) {
            const int r = lane;
            float lg[NEXP];
#pragma unroll
            for (int e = 0; e < NEXP; ++e) lg[e] = acc[r][e] + b[e];

            float mx = lg[0];
#pragma unroll
            for (int e = 1; e < NEXP; ++e) mx = fmaxf(mx, lg[e]);

            float p[NEXP];
            float sum = 0.0f;
#pragma unroll
            for (int e = 0; e < NEXP; ++e) { p[e] = __expf(lg[e] - mx); sum += p[e]; }
            const float inv = 1.0f / sum;

            // top-1: strict > keeps the lowest index on ties (jax.lax.top_k order)
            int i1 = 0;
#pragma unroll
            for (int e = 1; e < NEXP; ++e) if (lg[e] > lg[i1]) i1 = e;
            // top-2: lowest-index-first among the rest
            int i2 = (i1 == 0) ? 1 : 0;
#pragma unroll
            for (int e = 0; e < NEXP; ++e)
                if (e != i1 && e != i2 && lg[e] > lg[i2]) i2 = e;

            const int row = row0 + r;
            out_vals[row * 2 + 0] = p[i1] * inv;
            out_vals[row * 2 + 1] = p[i2] * inv;
            out_idx[row * 2 + 0]  = (float)i1;
            out_idx[row * 2 + 1]  = (float)i2;
        }
    }
}

extern "C" void kernel_launch(void* const* d_in, const int* in_sizes, int n_in,
                              void* d_out, int out_size, void* d_ws, size_t ws_size,
                              hipStream_t stream) {
    const float* x = (const float*)d_in[0];
    const float* W = (const float*)d_in[1];
    const float* b = (const float*)d_in[2];

    float* out = (float*)d_out;
    float* out_vals = out;                       // N*2
    float* out_idx  = out + (size_t)N_ROWS * 2;  // N*2
    float* out_x    = out + (size_t)N_ROWS * 4;  // N*D

    moe_router_kernel<<<GRID, BLOCK, 0, stream>>>(x, W, b, out_vals, out_idx, out_x);
}

// Round 7
// 216.801 us; speedup vs baseline: 3.1220x; 1.0311x over previous
//
#include <hip/hip_runtime.h>
#include <hip/hip_bf16.h>

#define N_ROWS 65536
#define DIM    2048
#define NEXP   8
#define TOPK   2
#define RPW    2                   // rows per wave per iteration
#define CHUNKS (DIM / (64 * 4))    // 8 float4-chunks per row per lane
#define BLOCK  1024                // 16 waves/block
#define GRID   512                 // 2 blocks/CU; 8192 waves; 4 iters each, exact

typedef float f4 __attribute__((ext_vector_type(4)));

// R6 config (223.5 us, 4.8 TB/s) + explicit 1-chunk software pipeline:
// prefetch chunk c+1's x while storing+computing chunk c, so the store
// stream isn't serialized behind each chunk's own load. Floor is the
// mixed-stream copy ceiling (~6.3 TB/s -> ~171 us for 1.076 GB).
__global__ __launch_bounds__(BLOCK, 4) void moe_router_kernel(
    const float* __restrict__ x,
    const float* __restrict__ W,
    const float* __restrict__ b,
    float* __restrict__ out_vals,   // [N, 2] f32
    float* __restrict__ out_idx,    // [N, 2] written as f32
    float* __restrict__ out_x)      // [N, D] f32 (pass-through copy)
{
    __shared__ float sW[NEXP * DIM];   // 64 KiB

    const f4* W4 = (const f4*)W;
    f4* sW4 = (f4*)sW;
    for (int i = threadIdx.x; i < NEXP * DIM / 4; i += BLOCK)
        sW4[i] = W4[i];
    __syncthreads();

    const int lane   = threadIdx.x & 63;
    const int wave   = (int)((blockIdx.x * BLOCK + threadIdx.x) >> 6);
    const int nwaves = (GRID * BLOCK) >> 6;

    const f4* x4 = (const f4*)x;
    f4* ox4 = (f4*)out_x;
    const int row_f4 = DIM / 4;   // 512 float4s per row

    for (int g = wave; g < N_ROWS / RPW; g += nwaves) {
        const int row0 = g * RPW;
        const size_t base0 = (size_t)row0 * row_f4 + lane;
        const size_t base1 = base0 + row_f4;

        float acc[RPW][NEXP];
#pragma unroll
        for (int r = 0; r < RPW; ++r)
#pragma unroll
            for (int e = 0; e < NEXP; ++e) acc[r][e] = 0.0f;

        // prologue: chunk 0 loads in flight
        f4 xv0 = x4[base0];
        f4 xv1 = x4[base1];

#pragma unroll 2
        for (int c = 0; c < CHUNKS; ++c) {
            const int d4 = c * 64 + lane;

            // prefetch next chunk (keeps >=2 chunks of loads outstanding)
            f4 xn0, xn1;
            if (c + 1 < CHUNKS) {
                xn0 = x4[base0 + (c + 1) * 64];
                xn1 = x4[base1 + (c + 1) * 64];
            }

            // store current chunk (fused pass-through copy) before the FMA block
            ox4[base0 + c * 64] = xv0;
            ox4[base1 + c * 64] = xv1;

#pragma unroll
            for (int e = 0; e < NEXP; ++e) {
                const f4 wv = sW4[e * row_f4 + d4];
                acc[0][e] += xv0.x * wv.x + xv0.y * wv.y + xv0.z * wv.z + xv0.w * wv.w;
                acc[1][e] += xv1.x * wv.x + xv1.y * wv.y + xv1.z * wv.z + xv1.w * wv.w;
            }

            xv0 = xn0;
            xv1 = xn1;
        }

        // Wave-wide butterfly reduce: every lane ends with the full dot product.
#pragma unroll
        for (int r = 0; r < RPW; ++r) {
#pragma unroll
            for (int e = 0; e < NEXP; ++e) {
                float v = acc[r][e];
                v += __shfl_xor(v, 32, 64);
                v += __shfl_xor(v, 16, 64);
                v += __shfl_xor(v, 8, 64);
                v += __shfl_xor(v, 4, 64);
                v += __shfl_xor(v, 2, 64);
                v += __shfl_xor(v, 1, 64);
                acc[r][e] = v;
            }
        }

        // Lanes 0..RPW-1 finish one row each: bias, softmax over 8, top-2.
        if (lane < RPW) {
            const int r = lane;
            float lg[NEXP];
#pragma unroll
            for (int e = 0; e < NEXP; ++e) lg[e] = acc[r][e] + b[e];

            float mx = lg[0];
#pragma unroll
            for (int e = 1; e < NEXP; ++e) mx = fmaxf(mx, lg[e]);

            float p[NEXP];
            float sum = 0.0f;
#pragma unroll
            for (int e = 0; e < NEXP; ++e) { p[e] = __expf(lg[e] - mx); sum += p[e]; }
            const float inv = 1.0f / sum;

            // top-1: strict > keeps the lowest index on ties (jax.lax.top_k order)
            int i1 = 0;
#pragma unroll
            for (int e = 1; e < NEXP; ++e) if (lg[e] > lg[i1]) i1 = e;
            // top-2: lowest-index-first among the rest
            int i2 = (i1 == 0) ? 1 : 0;
#pragma unroll
            for (int e = 0; e < NEXP; ++e)
                if (e != i1 && e != i2 && lg[e] > lg[i2]) i2 = e;

            const int row = row0 + r;
            out_vals[row * 2 + 0] = p[i1] * inv;
            out_vals[row * 2 + 1] = p[i2] * inv;
            out_idx[row * 2 + 0]  = (float)i1;
            out_idx[row * 2 + 1]  = (float)i2;
        }
    }
}

extern "C" void kernel_launch(void* const* d_in, const int* in_sizes, int n_in,
                              void* d_out, int out_size, void* d_ws, size_t ws_size,
                              hipStream_t stream) {
    const float* x = (const float*)d_in[0];
    const float* W = (const float*)d_in[1];
    const float* b = (const float*)d_in[2];

    float* out = (float*)d_out;
    float* out_vals = out;                       // N*2
    float* out_idx  = out + (size_t)N_ROWS * 2;  // N*2
    float* out_x    = out + (size_t)N_ROWS * 4;  // N*D

    moe_router_kernel<<<GRID, BLOCK, 0, stream>>>(x, W, b, out_vals, out_idx, out_x);
}